// Round 8
// baseline (1979.832 us; speedup 1.0000x reference)
//
#include <hip/hip_runtime.h>
#include <hip/hip_bf16.h>
#include <hip/hip_cooperative_groups.h>

namespace cg = cooperative_groups;

#define Bn 2
#define Tn 12
#define Hn 80
#define Wn 120
#define CIN 6
#define SITES (Hn * Wn)          // 9600
#define HSZ (4 * SITES * 32)     // 1228800 elements per state field
#define GRID 512                 // 4 fields x 16 yb x 8 seg
#define BLK 256

typedef __attribute__((ext_vector_type(8))) short short8;
typedef __attribute__((ext_vector_type(4))) float f32x4;

__device__ __forceinline__ short f2bf(float f) {
    union { __hip_bfloat16 h; short s; } u;
    u.h = __float2bfloat16(f);
    return u.s;
}
__device__ __forceinline__ float fast_sigmoid(float v) { return 1.f / (1.f + __expf(-v)); }
__device__ __forceinline__ float fast_tanh(float v) {
    v = fminf(fmaxf(v, -15.f), 15.f);
    float e = __expf(2.f * v);
    return (e - 1.f) / (e + 1.f);
}

#define SZR (2 * 64 * 288)
#define SWH (2 * 32 * 288)
#define SWX (2 * 96 * 96)
#define NPX (Bn * Tn * SITES)
#define PREP_TOT (SZR + SWH + SWX + NPX)   // 304128

// one pack item (round-6 proven layouts)
__device__ __forceinline__ void prep_item(
    int i,
    const float* Wzr_f, const float* Wzr_b, const float* Wh_f, const float* Wh_b,
    const float* Wx_f,  const float* Wx_b,  const float* x,
    short* wzrP, short* whP, short* wxP, short* xb8)
{
    if (i < SZR) {
        int dir = i / (64 * 288); int r = i % (64 * 288);
        int nn = r / 288, k = r % 288;
        const float* W = dir ? Wzr_b : Wzr_f;      // [tap][ci32][64]
        wzrP[i] = f2bf(W[k * 64 + nn]);
    } else if (i < SZR + SWH) {
        int j = i - SZR;
        int dir = j / (32 * 288); int r = j % (32 * 288);
        int nn = r / 288, k = r % 288;
        const float* W = dir ? Wh_b : Wh_f;        // [tap][ci32][32]
        whP[j] = f2bf(W[k * 32 + nn]);
    } else if (i < SZR + SWH + SWX) {
        int j = i - SZR - SWH;
        int dir = j / (96 * 96); int r = j % (96 * 96);
        int col = r / 96, k = r % 96;
        int chunk = k / 32, qq = (k % 32) / 8, jj = k % 8;
        int tap = chunk * 4 + qq;
        const float* W = dir ? Wx_b : Wx_f;        // [tap][ci6][96]
        wxP[j] = (tap < 9 && jj < 6) ? f2bf(W[(tap * CIN + jj) * 96 + col]) : (short)0;
    } else {
        int p = i - SZR - SWH - SWX;
        const float* xp = x + (size_t)p * CIN;
        short v[8];
        #pragma unroll
        for (int c = 0; c < CIN; c++) v[c] = f2bf(xp[c]);
        v[6] = 0; v[7] = 0;
        *(short8*)&xb8[(size_t)p * 8] = *(short8*)v;
    }
}

// One GRU time-step for one block: interior 5x16, halo 7x18=126 sites.
// Weights read from global (L2-hot). LDS: rh halo (bf16) + z tile (fp32) = 20640 B.
__device__ __forceinline__ void step_body(
    int s, int bid, int tid, short* rh_l, float* z_l,
    const short* xb8, const short* wzrP, const short* whP, const short* wxP,
    const float* b_f, const float* b_b,
    const short* hbp, short* hbc, const float* hfp, float* hfc,
    float* out)
{
    int seg = bid & 7;
    int t1  = bid >> 3;
    int yb  = t1 & 15;
    int field = t1 >> 4;
    int dir = field >> 1, b = field & 1;
    int y0 = yb * 5, x0 = seg * 16;
    int t = dir ? (Tn - 1 - s) : s;

    const short* xs   = xb8 + (size_t)((b * Tn + t) * SITES) * 8;
    const short* hbpf = hbp + (size_t)field * SITES * 32;
    short*       hbcf = hbc + (size_t)field * SITES * 32;
    const float* hfpf = hfp + (size_t)field * SITES * 32;
    float*       hfcf = hfc + (size_t)field * SITES * 32;
    const short* wzg = wzrP + dir * 64 * 288;
    const short* whg = whP  + dir * 32 * 288;
    const short* wxg = wxP  + dir * 96 * 96;
    const float* bias = dir ? b_b : b_f;

    int wid = tid >> 6, lane = tid & 63;
    int n = lane & 15, q = lane >> 4, q8 = q * 8;

    // ======== phase A: gates over the 7x18 halo ========
    #pragma unroll
    for (int rep = 0; rep < 2; rep++) {
        int ht = wid + rep * 4;            // 0..7
        int hs_l = ht * 16 + n;
        bool av = hs_l < 126;
        int hr = hs_l / 18, hc = hs_l - hr * 18;
        int gy = y0 - 1 + hr, gx = x0 - 1 + hc;

        f32x4 acc[4];
        #pragma unroll
        for (int nt = 0; nt < 4; nt++) acc[nt] = (f32x4)(bias[nt * 16 + n]);

        // x chunks (3 x K=32, tap = c*4+q; zero-padded weights for tap>=9)
        #pragma unroll
        for (int c = 0; c < 3; c++) {
            int tap = c * 4 + q;
            short8 a = (short8)(short)0;
            if (tap < 9 && av) {
                int ay = gy + tap / 3 - 1, ax = gx + tap % 3 - 1;
                if (ay >= 0 && ay < Hn && ax >= 0 && ax < Wn)
                    a = *(const short8*)&xs[(size_t)(ay * Wn + ax) * 8];
            }
            #pragma unroll
            for (int nt = 0; nt < 4; nt++) {
                short8 bf = *(const short8*)&wxg[(nt * 16 + n) * 96 + c * 32 + q8];
                acc[nt] = __builtin_amdgcn_mfma_f32_16x16x32_bf16(a, bf, acc[nt], 0, 0, 0);
            }
        }
        // h chunks (9 taps)
        if (s > 0) {
            #pragma unroll
            for (int ky = 0; ky < 3; ky++) {
                int ay = gy + ky - 1;
                bool rowok = (ay >= 0 && ay < Hn);
                #pragma unroll
                for (int kx = 0; kx < 3; kx++) {
                    int tap = ky * 3 + kx;
                    int ax = gx + kx - 1;
                    short8 a = (short8)(short)0;
                    if (av && rowok && ax >= 0 && ax < Wn)
                        a = *(const short8*)&hbpf[(size_t)(ay * Wn + ax) * 32 + q8];
                    #pragma unroll
                    for (int nt = 0; nt < 4; nt++) {
                        short8 bh = *(const short8*)&wzg[(nt * 16 + n) * 288 + tap * 32 + q8];
                        acc[nt] = __builtin_amdgcn_mfma_f32_16x16x32_bf16(a, bh, acc[nt], 0, 0, 0);
                    }
                }
            }
        }
        // epilogue: z -> LDS (interior only), r*h -> rh LDS (all halo sites)
        #pragma unroll
        for (int r = 0; r < 4; r++) {
            int hs_e = ht * 16 + q * 4 + r;
            if (hs_e >= 126) continue;
            int hr_e = hs_e / 18, hc_e = hs_e - hr_e * 18;
            int gy_e = y0 - 1 + hr_e, gx_e = x0 - 1 + hc_e;
            bool img = (gy_e >= 0 && gy_e < Hn && gx_e >= 0 && gx_e < Wn);
            bool inter = (hr_e >= 1 && hr_e <= 5 && hc_e >= 1 && hc_e <= 16);
            size_t pb = (size_t)(gy_e * Wn + gx_e) * 32;
            #pragma unroll
            for (int nt = 0; nt < 2; nt++) {
                if (img && inter)
                    z_l[((hr_e - 1) * 16 + hc_e - 1) * 33 + nt * 16 + n] = fast_sigmoid(acc[nt][r]);
            }
            #pragma unroll
            for (int nt = 2; nt < 4; nt++) {
                int ch = (nt - 2) * 16 + n;
                float rhv = 0.f;
                if (img && s > 0) rhv = fast_sigmoid(acc[nt][r]) * hfpf[pb + ch];
                rh_l[hs_e * 40 + ch] = f2bf(rhv);
            }
        }
    }
    __syncthreads();

    // ======== phase B: candidate conv + state update (interior 5 rows) ========
    #pragma unroll
    for (int rep = 0; rep < 2; rep++) {
        int ti = wid + rep * 4;            // valid < 5
        if (ti >= 5) continue;
        int y = y0 + ti, px = x0 + n;
        f32x4 acc2[2];
        #pragma unroll
        for (int ntc = 0; ntc < 2; ntc++) acc2[ntc] = (f32x4)(bias[64 + ntc * 16 + n]);

        // x chunks
        #pragma unroll
        for (int c = 0; c < 3; c++) {
            int tap = c * 4 + q;
            short8 a = (short8)(short)0;
            if (tap < 9) {
                int ay = y + tap / 3 - 1, ax = px + tap % 3 - 1;
                if (ay >= 0 && ay < Hn && ax >= 0 && ax < Wn)
                    a = *(const short8*)&xs[(size_t)(ay * Wn + ax) * 8];
            }
            #pragma unroll
            for (int ntc = 0; ntc < 2; ntc++) {
                short8 bf = *(const short8*)&wxg[(64 + ntc * 16 + n) * 96 + c * 32 + q8];
                acc2[ntc] = __builtin_amdgcn_mfma_f32_16x16x32_bf16(a, bf, acc2[ntc], 0, 0, 0);
            }
        }
        // rh chunks from LDS halo
        #pragma unroll
        for (int ky = 0; ky < 3; ky++) {
            #pragma unroll
            for (int kx = 0; kx < 3; kx++) {
                int tap = ky * 3 + kx;
                short8 a = *(const short8*)&rh_l[((ti + ky) * 18 + n + kx) * 40 + q8];
                #pragma unroll
                for (int ntc = 0; ntc < 2; ntc++) {
                    short8 bh = *(const short8*)&whg[(ntc * 16 + n) * 288 + tap * 32 + q8];
                    acc2[ntc] = __builtin_amdgcn_mfma_f32_16x16x32_bf16(a, bh, acc2[ntc], 0, 0, 0);
                }
            }
        }
        // epilogue
        #pragma unroll
        for (int r = 0; r < 4; r++) {
            int px_e = x0 + q * 4 + r;
            if (px_e >= Wn) continue;
            int site = y * Wn + px_e;
            size_t pb = (size_t)site * 32;
            #pragma unroll
            for (int ntc = 0; ntc < 2; ntc++) {
                int ch = ntc * 16 + n;
                float z  = z_l[(ti * 16 + q * 4 + r) * 33 + ch];
                float hh = fast_tanh(acc2[ntc][r]);
                float hp = (s > 0) ? hfpf[pb + ch] : 0.f;
                float hn = z * hp + (1.f - z) * hh;
                hbcf[pb + ch] = f2bf(hn);
                hfcf[pb + ch] = hn;
                out[((size_t)((b * Tn + t) * SITES) + site) * 64 + dir * 32 + ch] = hn;
            }
        }
    }
}

// ---- persistent cooperative kernel ----
__global__ __launch_bounds__(BLK, 2) void gru_persist(
    const float* __restrict__ x,
    const float* __restrict__ Wzr_f, const float* __restrict__ Wzr_b,
    const float* __restrict__ Wh_f,  const float* __restrict__ Wh_b,
    const float* __restrict__ Wx_f,  const float* __restrict__ Wx_b,
    const float* __restrict__ b_f,   const float* __restrict__ b_b,
    short* wzrP, short* whP, short* wxP, short* xb8,
    short* hb0, short* hb1, float* hf0, float* hf1,
    float* out)
{
    cg::grid_group gg = cg::this_grid();
    __shared__ short rh_l[126 * 40];   // 10080 B
    __shared__ float z_l[80 * 33];     // 10560 B
    int tid = threadIdx.x, bid = blockIdx.x;

    for (int i = bid * BLK + tid; i < PREP_TOT; i += GRID * BLK)
        prep_item(i, Wzr_f, Wzr_b, Wh_f, Wh_b, Wx_f, Wx_b, x, wzrP, whP, wxP, xb8);
    __threadfence();
    gg.sync();

    for (int s = 0; s < Tn; s++) {
        const short* hbp = (s & 1) ? hb0 : hb1;
        short*       hbc = (s & 1) ? hb1 : hb0;
        const float* hfp = (s & 1) ? hf0 : hf1;
        float*       hfc = (s & 1) ? hf1 : hf0;
        step_body(s, bid, tid, rh_l, z_l, xb8, wzrP, whP, wxP, b_f, b_b,
                  hbp, hbc, hfp, hfc, out);
        if (s < Tn - 1) { __threadfence(); gg.sync(); }
    }
}

// ---- fallback path (no grid sync needed: kernel boundaries give coherence) ----
__global__ __launch_bounds__(BLK) void prep_kernel(
    const float* __restrict__ Wzr_f, const float* __restrict__ Wzr_b,
    const float* __restrict__ Wh_f,  const float* __restrict__ Wh_b,
    const float* __restrict__ Wx_f,  const float* __restrict__ Wx_b,
    const float* __restrict__ x,
    short* wzrP, short* whP, short* wxP, short* xb8)
{
    int i = blockIdx.x * BLK + threadIdx.x;
    if (i < PREP_TOT)
        prep_item(i, Wzr_f, Wzr_b, Wh_f, Wh_b, Wx_f, Wx_b, x, wzrP, whP, wxP, xb8);
}

__global__ __launch_bounds__(BLK, 2) void step_kernel(
    const short* __restrict__ xb8, const short* __restrict__ wzrP,
    const short* __restrict__ whP, const short* __restrict__ wxP,
    const float* __restrict__ b_f, const float* __restrict__ b_b,
    const short* __restrict__ hbp, short* __restrict__ hbc,
    const float* __restrict__ hfp, float* __restrict__ hfc,
    float* __restrict__ out, int s)
{
    __shared__ short rh_l[126 * 40];
    __shared__ float z_l[80 * 33];
    step_body(s, blockIdx.x, threadIdx.x, rh_l, z_l, xb8, wzrP, whP, wxP,
              b_f, b_b, hbp, hbc, hfp, hfc, out);
}

extern "C" void kernel_launch(void* const* d_in, const int* in_sizes, int n_in,
                              void* d_out, int out_size, void* d_ws, size_t ws_size,
                              hipStream_t stream)
{
    const float* x     = (const float*)d_in[0];
    const float* Wx_f  = (const float*)d_in[1];
    const float* b_f   = (const float*)d_in[2];
    const float* Wzr_f = (const float*)d_in[3];
    const float* Wh_f  = (const float*)d_in[4];
    const float* Wx_b  = (const float*)d_in[5];
    const float* b_b   = (const float*)d_in[6];
    const float* Wzr_b = (const float*)d_in[7];
    const float* Wh_b  = (const float*)d_in[8];
    float* out = (float*)d_out;

    char* w = (char*)d_ws;
    short* hb0  = (short*)w;  w += (size_t)HSZ * 2;
    short* hb1  = (short*)w;  w += (size_t)HSZ * 2;
    float* hf0  = (float*)w;  w += (size_t)HSZ * 4;
    float* hf1  = (float*)w;  w += (size_t)HSZ * 4;
    short* xb8  = (short*)w;  w += (size_t)NPX * 8 * 2;
    short* wzrP = (short*)w;  w += (size_t)SZR * 2;
    short* whP  = (short*)w;  w += (size_t)SWH * 2;
    short* wxP  = (short*)w;  w += (size_t)SWX * 2;

    void* args[] = { (void*)&x,
                     (void*)&Wzr_f, (void*)&Wzr_b,
                     (void*)&Wh_f,  (void*)&Wh_b,
                     (void*)&Wx_f,  (void*)&Wx_b,
                     (void*)&b_f,   (void*)&b_b,
                     (void*)&wzrP,  (void*)&whP, (void*)&wxP, (void*)&xb8,
                     (void*)&hb0,   (void*)&hb1, (void*)&hf0, (void*)&hf1,
                     (void*)&out };
    hipError_t err = hipLaunchCooperativeKernel((const void*)gru_persist,
                                                dim3(GRID), dim3(BLK), args, 0, stream);
    if (err != hipSuccess) {
        (void)hipGetLastError();   // clear sticky error, use fallback
        prep_kernel<<<(PREP_TOT + BLK - 1) / BLK, BLK, 0, stream>>>(
            Wzr_f, Wzr_b, Wh_f, Wh_b, Wx_f, Wx_b, x, wzrP, whP, wxP, xb8);
        for (int s = 0; s < Tn; s++) {
            const short* hbp = (s & 1) ? hb0 : hb1;
            short*       hbc = (s & 1) ? hb1 : hb0;
            const float* hfp = (s & 1) ? hf0 : hf1;
            float*       hfc = (s & 1) ? hf1 : hf0;
            step_kernel<<<GRID, BLK, 0, stream>>>(xb8, wzrP, whP, wxP, b_f, b_b,
                                                  hbp, hbc, hfp, hfc, out, s);
        }
    }
}

// Round 9
// 371.475 us; speedup vs baseline: 5.3297x; 5.3297x over previous
//
#include <hip/hip_runtime.h>
#include <hip/hip_bf16.h>

#define Bn 2
#define Tn 12
#define Hn 80
#define Wn 120
#define CIN 6
#define SITES (Hn * Wn)          // 9600
#define HSZ (4 * SITES * 32)     // 1228800 elements per state field
#define GRID 512                 // 4 fields x 16 yb x 8 seg
#define BLK 256
#define CTILE (GRID * 5 * 2 * 256)   // hfC elements: block x ti x ntc x lane*4

typedef __attribute__((ext_vector_type(8))) short short8;
typedef __attribute__((ext_vector_type(4))) float f32x4;

__device__ __forceinline__ short f2bf(float f) {
    union { __hip_bfloat16 h; short s; } u;
    u.h = __float2bfloat16(f);
    return u.s;
}
__device__ __forceinline__ float bf2f(short s) {
    union { float f; unsigned u; } u;
    u.u = ((unsigned)(unsigned short)s) << 16;
    return u.f;
}
__device__ __forceinline__ float fast_sigmoid(float v) { return 1.f / (1.f + __expf(-v)); }
__device__ __forceinline__ float fast_tanh(float v) {
    v = fminf(fmaxf(v, -15.f), 15.f);
    float e = __expf(2.f * v);
    return (e - 1.f) / (e + 1.f);
}

#define SZR (2 * 64 * 288)
#define SWH (2 * 32 * 288)
#define SWX (2 * 96 * 96)
#define NPX (Bn * Tn * SITES)
#define PREP_TOT (SZR + SWH + SWX + NPX)   // 304128

// ---- prologue: pack weights (transposed bf16) + x (padded bf16x8) ----
__global__ __launch_bounds__(BLK) void prep_kernel(
    const float* __restrict__ Wzr_f, const float* __restrict__ Wzr_b,
    const float* __restrict__ Wh_f,  const float* __restrict__ Wh_b,
    const float* __restrict__ Wx_f,  const float* __restrict__ Wx_b,
    const float* __restrict__ x,
    short* __restrict__ wzrP, short* __restrict__ whP, short* __restrict__ wxP,
    short* __restrict__ xb8)
{
    int i = blockIdx.x * BLK + threadIdx.x;
    if (i < SZR) {
        int dir = i / (64 * 288); int r = i % (64 * 288);
        int nn = r / 288, k = r % 288;
        const float* W = dir ? Wzr_b : Wzr_f;      // [tap][ci32][64]
        wzrP[i] = f2bf(W[k * 64 + nn]);
    } else if (i < SZR + SWH) {
        int j = i - SZR;
        int dir = j / (32 * 288); int r = j % (32 * 288);
        int nn = r / 288, k = r % 288;
        const float* W = dir ? Wh_b : Wh_f;        // [tap][ci32][32]
        whP[j] = f2bf(W[k * 32 + nn]);
    } else if (i < SZR + SWH + SWX) {
        int j = i - SZR - SWH;
        int dir = j / (96 * 96); int r = j % (96 * 96);
        int col = r / 96, k = r % 96;
        int chunk = k / 32, qq = (k % 32) / 8, jj = k % 8;
        int tap = chunk * 4 + qq;
        const float* W = dir ? Wx_b : Wx_f;        // [tap][ci6][96]
        wxP[j] = (tap < 9 && jj < 6) ? f2bf(W[(tap * CIN + jj) * 96 + col]) : (short)0;
    } else if (i < PREP_TOT) {
        int p = i - SZR - SWH - SWX;
        const float* xp = x + (size_t)p * CIN;
        short v[8];
        #pragma unroll
        for (int c = 0; c < CIN; c++) v[c] = f2bf(xp[c]);
        v[6] = 0; v[7] = 0;
        *(short8*)&xb8[(size_t)p * 8] = *(short8*)v;
    }
}

// ---- fused GRU step: gates over 7x18 halo -> LDS, candidate + update ----
// hfC layout: [bid][ti5][ntc2][lane64][r4] fp32 (block-owned interior tiles)
__global__ __launch_bounds__(BLK, 2) void step_kernel(
    const short* __restrict__ xb8, const short* __restrict__ wzrP,
    const short* __restrict__ whP, const short* __restrict__ wxP,
    const float* __restrict__ b_f, const float* __restrict__ b_b,
    const short* __restrict__ hbp, short* __restrict__ hbc,
    const float* __restrict__ hfCp, float* __restrict__ hfCc,
    float* __restrict__ out, int s)
{
    __shared__ short rh_l[126 * 40];   // 10080 B  (r*h bf16, halo 7x18)
    __shared__ float z_l[80 * 33];     // 10560 B  (z fp32, interior 5x16)

    int tid = threadIdx.x, bid = blockIdx.x;
    int seg = bid & 7;
    int t1  = bid >> 3;
    int yb  = t1 & 15;
    int field = t1 >> 4;
    int dir = field >> 1, b = field & 1;
    int y0 = yb * 5, x0 = seg * 16;
    int t = dir ? (Tn - 1 - s) : s;

    const short* xs   = xb8 + (size_t)((b * Tn + t) * SITES) * 8;
    const short* hbpf = hbp + (size_t)field * SITES * 32;
    short*       hbcf = hbc + (size_t)field * SITES * 32;
    const short* wzg = wzrP + dir * 64 * 288;
    const short* whg = whP  + dir * 32 * 288;
    const short* wxg = wxP  + dir * 96 * 96;
    const float* bias = dir ? b_b : b_f;

    int wid = tid >> 6, lane = tid & 63;
    int n = lane & 15, q = lane >> 4, q8 = q * 8;

    // ======== phase A: gates over the 7x18 halo (8 tiles over 2 reps) ========
    #pragma unroll
    for (int rep = 0; rep < 2; rep++) {
        int ht = wid + rep * 4;            // 0..7
        int hs_l = ht * 16 + n;
        bool av = hs_l < 126;
        int hr = hs_l / 18, hc = hs_l - hr * 18;
        int gy = y0 - 1 + hr, gx = x0 - 1 + hc;

        f32x4 acc[4];
        #pragma unroll
        for (int nt = 0; nt < 4; nt++) acc[nt] = (f32x4)(bias[nt * 16 + n]);

        // x chunks (3 x K=32, tap = c*4+q; zero-padded weights for tap>=9)
        #pragma unroll
        for (int c = 0; c < 3; c++) {
            int tap = c * 4 + q;
            short8 a = (short8)(short)0;
            if (tap < 9 && av) {
                int ay = gy + tap / 3 - 1, ax = gx + tap % 3 - 1;
                if (ay >= 0 && ay < Hn && ax >= 0 && ax < Wn)
                    a = *(const short8*)&xs[(size_t)(ay * Wn + ax) * 8];
            }
            #pragma unroll
            for (int nt = 0; nt < 4; nt++) {
                short8 bf = *(const short8*)&wxg[(nt * 16 + n) * 96 + c * 32 + q8];
                acc[nt] = __builtin_amdgcn_mfma_f32_16x16x32_bf16(a, bf, acc[nt], 0, 0, 0);
            }
        }
        // h chunks (9 taps)
        if (s > 0) {
            #pragma unroll
            for (int ky = 0; ky < 3; ky++) {
                int ay = gy + ky - 1;
                bool rowok = (ay >= 0 && ay < Hn);
                #pragma unroll
                for (int kx = 0; kx < 3; kx++) {
                    int tap = ky * 3 + kx;
                    int ax = gx + kx - 1;
                    short8 a = (short8)(short)0;
                    if (av && rowok && ax >= 0 && ax < Wn)
                        a = *(const short8*)&hbpf[(size_t)(ay * Wn + ax) * 32 + q8];
                    #pragma unroll
                    for (int nt = 0; nt < 4; nt++) {
                        short8 bh = *(const short8*)&wzg[(nt * 16 + n) * 288 + tap * 32 + q8];
                        acc[nt] = __builtin_amdgcn_mfma_f32_16x16x32_bf16(a, bh, acc[nt], 0, 0, 0);
                    }
                }
            }
        }
        // epilogue: z -> LDS (interior), r * h(bf16) -> rh LDS (all halo sites)
        #pragma unroll
        for (int r = 0; r < 4; r++) {
            int hs_e = ht * 16 + q * 4 + r;
            if (hs_e >= 126) continue;
            int hr_e = hs_e / 18, hc_e = hs_e - hr_e * 18;
            int gy_e = y0 - 1 + hr_e, gx_e = x0 - 1 + hc_e;
            bool img = (gy_e >= 0 && gy_e < Hn && gx_e >= 0 && gx_e < Wn);
            bool inter = (hr_e >= 1 && hr_e <= 5 && hc_e >= 1 && hc_e <= 16);
            size_t pb = (size_t)(gy_e * Wn + gx_e) * 32;
            #pragma unroll
            for (int nt = 0; nt < 2; nt++) {
                if (img && inter)
                    z_l[((hr_e - 1) * 16 + hc_e - 1) * 33 + nt * 16 + n] = fast_sigmoid(acc[nt][r]);
            }
            #pragma unroll
            for (int nt = 2; nt < 4; nt++) {
                int ch = (nt - 2) * 16 + n;
                float rhv = 0.f;
                if (img && s > 0)
                    rhv = fast_sigmoid(acc[nt][r]) * bf2f(hbpf[pb + ch]);
                rh_l[hs_e * 40 + ch] = f2bf(rhv);
            }
        }
    }
    __syncthreads();

    // ======== phase B: candidate conv + state update (interior 5 rows) ========
    #pragma unroll
    for (int rep = 0; rep < 2; rep++) {
        int ti = wid + rep * 4;            // valid < 5
        if (ti >= 5) continue;
        int y = y0 + ti, px = x0 + n;
        f32x4 acc2[2];
        #pragma unroll
        for (int ntc = 0; ntc < 2; ntc++) acc2[ntc] = (f32x4)(bias[64 + ntc * 16 + n]);

        // x chunks
        #pragma unroll
        for (int c = 0; c < 3; c++) {
            int tap = c * 4 + q;
            short8 a = (short8)(short)0;
            if (tap < 9) {
                int ay = y + tap / 3 - 1, ax = px + tap % 3 - 1;
                if (ay >= 0 && ay < Hn && ax >= 0 && ax < Wn)
                    a = *(const short8*)&xs[(size_t)(ay * Wn + ax) * 8];
            }
            #pragma unroll
            for (int ntc = 0; ntc < 2; ntc++) {
                short8 bf = *(const short8*)&wxg[(64 + ntc * 16 + n) * 96 + c * 32 + q8];
                acc2[ntc] = __builtin_amdgcn_mfma_f32_16x16x32_bf16(a, bf, acc2[ntc], 0, 0, 0);
            }
        }
        // rh chunks from LDS halo
        #pragma unroll
        for (int ky = 0; ky < 3; ky++) {
            #pragma unroll
            for (int kx = 0; kx < 3; kx++) {
                int tap = ky * 3 + kx;
                short8 a = *(const short8*)&rh_l[((ti + ky) * 18 + n + kx) * 40 + q8];
                #pragma unroll
                for (int ntc = 0; ntc < 2; ntc++) {
                    short8 bh = *(const short8*)&whg[(ntc * 16 + n) * 288 + tap * 32 + q8];
                    acc2[ntc] = __builtin_amdgcn_mfma_f32_16x16x32_bf16(a, bh, acc2[ntc], 0, 0, 0);
                }
            }
        }
        // epilogue: h = z*h_prev + (1-z)*tanh(.)  (state vectorized via C-layout)
        #pragma unroll
        for (int ntc = 0; ntc < 2; ntc++) {
            size_t cofs = (((size_t)bid * 5 + ti) * 2 + ntc) * 256 + lane * 4;
            f32x4 hp = (f32x4)0.f;
            if (s > 0) hp = *(const f32x4*)&hfCp[cofs];
            f32x4 hn;
            #pragma unroll
            for (int r = 0; r < 4; r++) {
                float z  = z_l[(ti * 16 + q * 4 + r) * 33 + ntc * 16 + n];
                float hh = fast_tanh(acc2[ntc][r]);
                hn[r] = z * hp[r] + (1.f - z) * hh;
            }
            *(f32x4*)&hfCc[cofs] = hn;
            #pragma unroll
            for (int r = 0; r < 4; r++) {
                int px_e = x0 + q * 4 + r;
                if (px_e >= Wn) continue;
                int site = y * Wn + px_e;
                int ch = ntc * 16 + n;
                hbcf[(size_t)site * 32 + ch] = f2bf(hn[r]);
                __builtin_nontemporal_store(hn[r],
                    &out[((size_t)((b * Tn + t) * SITES) + site) * 64 + dir * 32 + ch]);
            }
        }
    }
}

extern "C" void kernel_launch(void* const* d_in, const int* in_sizes, int n_in,
                              void* d_out, int out_size, void* d_ws, size_t ws_size,
                              hipStream_t stream)
{
    const float* x     = (const float*)d_in[0];
    const float* Wx_f  = (const float*)d_in[1];
    const float* b_f   = (const float*)d_in[2];
    const float* Wzr_f = (const float*)d_in[3];
    const float* Wh_f  = (const float*)d_in[4];
    const float* Wx_b  = (const float*)d_in[5];
    const float* b_b   = (const float*)d_in[6];
    const float* Wzr_b = (const float*)d_in[7];
    const float* Wh_b  = (const float*)d_in[8];
    float* out = (float*)d_out;

    char* w = (char*)d_ws;
    short* hb0  = (short*)w;  w += (size_t)HSZ * 2;
    short* hb1  = (short*)w;  w += (size_t)HSZ * 2;
    float* hfC0 = (float*)w;  w += (size_t)CTILE * 4;
    float* hfC1 = (float*)w;  w += (size_t)CTILE * 4;
    short* xb8  = (short*)w;  w += (size_t)NPX * 8 * 2;
    short* wzrP = (short*)w;  w += (size_t)SZR * 2;
    short* whP  = (short*)w;  w += (size_t)SWH * 2;
    short* wxP  = (short*)w;  w += (size_t)SWX * 2;
    // total ~19.7 MB

    prep_kernel<<<(PREP_TOT + BLK - 1) / BLK, BLK, 0, stream>>>(
        Wzr_f, Wzr_b, Wh_f, Wh_b, Wx_f, Wx_b, x, wzrP, whP, wxP, xb8);

    for (int s = 0; s < Tn; s++) {
        const short* hbp = (s & 1) ? hb0 : hb1;
        short*       hbc = (s & 1) ? hb1 : hb0;
        const float* hfp = (s & 1) ? hfC0 : hfC1;
        float*       hfc = (s & 1) ? hfC1 : hfC0;
        step_kernel<<<GRID, BLK, 0, stream>>>(xb8, wzrP, whP, wxP, b_f, b_b,
                                              hbp, hbc, hfp, hfc, out, s);
    }
}

// Round 10
// 284.280 us; speedup vs baseline: 6.9644x; 1.3067x over previous
//
#include <hip/hip_runtime.h>
#include <hip/hip_bf16.h>

#define Bn 2
#define Tn 12
#define Hn 80
#define Wn 120
#define CIN 6
#define SITES (Hn * Wn)          // 9600
#define HSZ (4 * SITES * 32)     // 1228800 elements per bf16 state field
#define GRID 512                 // 4 fields x 16 yb x 8 seg
#define BLK 256
#define CTILE (GRID * 5 * 2 * 256)   // hfC elements: block x ti x ntc x lane*4

#define NA_D (48 * 64 * 8)       // gates operand-order B set, per dir (24576 shorts)
#define NB_D (24 * 64 * 8)       // candidate set per dir (12288 shorts)
#define NA (2 * NA_D)
#define NB (2 * NB_D)
#define NPX (Bn * Tn * SITES)
#define PREP_TOT (NA + NB + NPX) // 304128

typedef __attribute__((ext_vector_type(8))) short short8;
typedef __attribute__((ext_vector_type(4))) float f32x4;

__device__ __forceinline__ short f2bf(float f) {
    union { __hip_bfloat16 h; short s; } u;
    u.h = __float2bfloat16(f);
    return u.s;
}
__device__ __forceinline__ float bf2f(short s) {
    union { float f; unsigned u; } u;
    u.u = ((unsigned)(unsigned short)s) << 16;
    return u.f;
}
__device__ __forceinline__ float fast_sigmoid(float v) { return 1.f / (1.f + __expf(-v)); }
__device__ __forceinline__ float fast_tanh(float v) {
    v = fminf(fmaxf(v, -15.f), 15.f);
    float e = __expf(2.f * v);
    return (e - 1.f) / (e + 1.f);
}

// ---- prologue: expand weights to MFMA-operand order + pack x to padded bf16x8 ----
// bopA[dir][chunk12*4+nt][lane64][8]: chunk 0..2 = x (tap=chunk*4+q), 3..11 = h (tap=chunk-3)
// bopB[dir][chunk12*2+ntc][lane64][8]: same chunks, candidate cols
__global__ __launch_bounds__(BLK) void prep_kernel(
    const float* __restrict__ Wzr_f, const float* __restrict__ Wzr_b,
    const float* __restrict__ Wh_f,  const float* __restrict__ Wh_b,
    const float* __restrict__ Wx_f,  const float* __restrict__ Wx_b,
    const float* __restrict__ x,
    short* __restrict__ bopA, short* __restrict__ bopB, short* __restrict__ xb8)
{
    int i = blockIdx.x * BLK + threadIdx.x;
    if (i < NA) {
        int dir = i / NA_D; int r = i % NA_D;
        int f = r / 512; int lane = (r % 512) / 8; int j = r % 8;
        int q = lane >> 4, n = lane & 15;
        int chunk = f >> 2, nt = f & 3;
        float v = 0.f;
        if (chunk < 3) {
            int tap = chunk * 4 + q;
            if (tap < 9 && j < 6) v = (dir ? Wx_b : Wx_f)[(tap * CIN + j) * 96 + nt * 16 + n];
        } else {
            int tap = chunk - 3;
            v = (dir ? Wzr_b : Wzr_f)[(tap * 32 + q * 8 + j) * 64 + nt * 16 + n];
        }
        bopA[i] = f2bf(v);
    } else if (i < NA + NB) {
        int ii = i - NA;
        int dir = ii / NB_D; int r = ii % NB_D;
        int f = r / 512; int lane = (r % 512) / 8; int j = r % 8;
        int q = lane >> 4, n = lane & 15;
        int chunk = f >> 1, ntc = f & 1;
        float v = 0.f;
        if (chunk < 3) {
            int tap = chunk * 4 + q;
            if (tap < 9 && j < 6) v = (dir ? Wx_b : Wx_f)[(tap * CIN + j) * 96 + 64 + ntc * 16 + n];
        } else {
            int tap = chunk - 3;
            v = (dir ? Wh_b : Wh_f)[(tap * 32 + q * 8 + j) * 32 + ntc * 16 + n];
        }
        bopB[ii] = f2bf(v);
    } else if (i < PREP_TOT) {
        int p = i - NA - NB;
        const float* xp = x + (size_t)p * CIN;
        short v[8];
        #pragma unroll
        for (int c = 0; c < CIN; c++) v[c] = f2bf(xp[c]);
        v[6] = 0; v[7] = 0;
        *(short8*)&xb8[(size_t)p * 8] = *(short8*)v;
    }
}

// ---- fused GRU step, M=32 pairing: each wave owns TWO tiles sharing every B-frag ----
__global__ __launch_bounds__(BLK, 2) void step_kernel(
    const short* __restrict__ xb8,
    const short* __restrict__ bopA, const short* __restrict__ bopB,
    const float* __restrict__ b_f, const float* __restrict__ b_b,
    const short* __restrict__ hbp, short* __restrict__ hbc,
    const float* __restrict__ hfCp, float* __restrict__ hfCc,
    float* __restrict__ out, int s)
{
    __shared__ short rh_l[126 * 40];   // 10080 B  (r*h bf16, halo 7x18)
    __shared__ float z_l[80 * 33];     // 10560 B  (z fp32, interior 5x16)

    int tid = threadIdx.x, bid = blockIdx.x;
    int seg = bid & 7;
    int t1  = bid >> 3;
    int yb  = t1 & 15;
    int field = t1 >> 4;
    int dir = field >> 1, b = field & 1;
    int y0 = yb * 5, x0 = seg * 16;
    int t = dir ? (Tn - 1 - s) : s;

    const short* xs   = xb8 + (size_t)((b * Tn + t) * SITES) * 8;
    const short* hbpf = hbp + (size_t)field * SITES * 32;
    short*       hbcf = hbc + (size_t)field * SITES * 32;
    const short* bA = bopA + dir * NA_D;
    const short* bB = bopB + dir * NB_D;
    const float* bias = dir ? b_b : b_f;

    int wid = tid >> 6, lane = tid & 63;
    int n = lane & 15, q = lane >> 4, q8 = q * 8;

    // ======== phase A: gates over 7x18 halo; wave wid -> tiles 2wid, 2wid+1 ========
    {
        int hs0 = (wid * 2) * 16 + n, hs1 = hs0 + 16;
        bool av0 = hs0 < 126, av1 = hs1 < 126;
        int hr0 = hs0 / 18, hc0 = hs0 - hr0 * 18;
        int hr1 = hs1 / 18, hc1 = hs1 - hr1 * 18;
        int gy0 = y0 - 1 + hr0, gx0 = x0 - 1 + hc0;
        int gy1 = y0 - 1 + hr1, gx1 = x0 - 1 + hc1;

        f32x4 acc[2][4];
        #pragma unroll
        for (int nt = 0; nt < 4; nt++) {
            float bv = bias[nt * 16 + n];
            acc[0][nt] = (f32x4)bv; acc[1][nt] = (f32x4)bv;
        }

        #pragma unroll
        for (int chunk = 0; chunk < 12; chunk++) {
            short8 a0 = (short8)(short)0, a1 = (short8)(short)0;
            if (chunk < 3) {
                int tap = chunk * 4 + q;
                if (tap < 9) {
                    int dy = tap / 3 - 1, dx = tap % 3 - 1;
                    int ay0 = gy0 + dy, ax0 = gx0 + dx;
                    int ay1 = gy1 + dy, ax1 = gx1 + dx;
                    if (av0 && ay0 >= 0 && ay0 < Hn && ax0 >= 0 && ax0 < Wn)
                        a0 = *(const short8*)&xs[(size_t)(ay0 * Wn + ax0) * 8];
                    if (av1 && ay1 >= 0 && ay1 < Hn && ax1 >= 0 && ax1 < Wn)
                        a1 = *(const short8*)&xs[(size_t)(ay1 * Wn + ax1) * 8];
                }
            } else {
                if (s == 0) continue;
                int tap = chunk - 3;
                int dy = tap / 3 - 1, dx = tap % 3 - 1;
                int ay0 = gy0 + dy, ax0 = gx0 + dx;
                int ay1 = gy1 + dy, ax1 = gx1 + dx;
                if (av0 && ay0 >= 0 && ay0 < Hn && ax0 >= 0 && ax0 < Wn)
                    a0 = *(const short8*)&hbpf[(size_t)(ay0 * Wn + ax0) * 32 + q8];
                if (av1 && ay1 >= 0 && ay1 < Hn && ax1 >= 0 && ax1 < Wn)
                    a1 = *(const short8*)&hbpf[(size_t)(ay1 * Wn + ax1) * 32 + q8];
            }
            #pragma unroll
            for (int nt = 0; nt < 4; nt++) {
                short8 B = *(const short8*)&bA[((chunk * 4 + nt) * 64 + lane) * 8];
                acc[0][nt] = __builtin_amdgcn_mfma_f32_16x16x32_bf16(a0, B, acc[0][nt], 0, 0, 0);
                acc[1][nt] = __builtin_amdgcn_mfma_f32_16x16x32_bf16(a1, B, acc[1][nt], 0, 0, 0);
            }
        }

        // epilogue: z -> LDS (interior), r * h(bf16) -> rh LDS (all halo sites)
        #pragma unroll
        for (int tl = 0; tl < 2; tl++) {
            int ht = wid * 2 + tl;
            #pragma unroll
            for (int r = 0; r < 4; r++) {
                int hs_e = ht * 16 + q * 4 + r;
                if (hs_e >= 126) continue;
                int hr_e = hs_e / 18, hc_e = hs_e - hr_e * 18;
                int gy_e = y0 - 1 + hr_e, gx_e = x0 - 1 + hc_e;
                bool img = (gy_e >= 0 && gy_e < Hn && gx_e >= 0 && gx_e < Wn);
                bool inter = (hr_e >= 1 && hr_e <= 5 && hc_e >= 1 && hc_e <= 16);
                size_t pb = (size_t)(gy_e * Wn + gx_e) * 32;
                #pragma unroll
                for (int nt = 0; nt < 2; nt++) {
                    if (img && inter)
                        z_l[((hr_e - 1) * 16 + hc_e - 1) * 33 + nt * 16 + n] =
                            fast_sigmoid(acc[tl][nt][r]);
                }
                #pragma unroll
                for (int nt = 2; nt < 4; nt++) {
                    int ch = (nt - 2) * 16 + n;
                    float rhv = 0.f;
                    if (img && s > 0)
                        rhv = fast_sigmoid(acc[tl][nt][r]) * bf2f(hbpf[pb + ch]);
                    rh_l[hs_e * 40 + ch] = f2bf(rhv);
                }
            }
        }
    }
    __syncthreads();

    // ======== phase B: candidate + update; wave wid -> interior tiles 2wid, 2wid+1 (<5) ========
    {
        int t0 = wid * 2;
        bool v0 = (t0 < 5), v1 = (t0 + 1 < 5);
        if (v0) {
            int tc0 = t0, tc1 = v1 ? t0 + 1 : t0;
            int yB0 = y0 + tc0, yB1 = y0 + tc1;

            f32x4 acc2[2][2];
            #pragma unroll
            for (int ntc = 0; ntc < 2; ntc++) {
                float bv = bias[64 + ntc * 16 + n];
                acc2[0][ntc] = (f32x4)bv; acc2[1][ntc] = (f32x4)bv;
            }

            #pragma unroll
            for (int chunk = 0; chunk < 12; chunk++) {
                short8 a0 = (short8)(short)0, a1 = (short8)(short)0;
                if (chunk < 3) {
                    int tap = chunk * 4 + q;
                    if (tap < 9) {
                        int dy = tap / 3 - 1, dx = tap % 3 - 1;
                        int ax = x0 + n + dx;
                        int ay0 = yB0 + dy, ay1 = yB1 + dy;
                        if (ay0 >= 0 && ay0 < Hn && ax >= 0 && ax < Wn)
                            a0 = *(const short8*)&xs[(size_t)(ay0 * Wn + ax) * 8];
                        if (ay1 >= 0 && ay1 < Hn && ax >= 0 && ax < Wn)
                            a1 = *(const short8*)&xs[(size_t)(ay1 * Wn + ax) * 8];
                    }
                } else {
                    int tap = chunk - 3;
                    int ky = tap / 3, kx = tap % 3;
                    a0 = *(const short8*)&rh_l[((tc0 + ky) * 18 + n + kx) * 40 + q8];
                    a1 = *(const short8*)&rh_l[((tc1 + ky) * 18 + n + kx) * 40 + q8];
                }
                #pragma unroll
                for (int ntc = 0; ntc < 2; ntc++) {
                    short8 B = *(const short8*)&bB[((chunk * 2 + ntc) * 64 + lane) * 8];
                    acc2[0][ntc] = __builtin_amdgcn_mfma_f32_16x16x32_bf16(a0, B, acc2[0][ntc], 0, 0, 0);
                    acc2[1][ntc] = __builtin_amdgcn_mfma_f32_16x16x32_bf16(a1, B, acc2[1][ntc], 0, 0, 0);
                }
            }

            // epilogue per valid tile: h = z*h_prev + (1-z)*tanh(.)
            #pragma unroll
            for (int tl = 0; tl < 2; tl++) {
                if (tl == 1 && !v1) continue;
                int ti = t0 + tl;
                int y = y0 + ti;
                #pragma unroll
                for (int ntc = 0; ntc < 2; ntc++) {
                    size_t cofs = (((size_t)bid * 5 + ti) * 2 + ntc) * 256 + lane * 4;
                    f32x4 hp = (f32x4)0.f;
                    if (s > 0) hp = *(const f32x4*)&hfCp[cofs];
                    f32x4 hn;
                    #pragma unroll
                    for (int r = 0; r < 4; r++) {
                        float z  = z_l[(ti * 16 + q * 4 + r) * 33 + ntc * 16 + n];
                        float hh = fast_tanh(acc2[tl][ntc][r]);
                        hn[r] = z * hp[r] + (1.f - z) * hh;
                    }
                    *(f32x4*)&hfCc[cofs] = hn;
                    #pragma unroll
                    for (int r = 0; r < 4; r++) {
                        int px_e = x0 + q * 4 + r;
                        if (px_e >= Wn) continue;
                        int site = y * Wn + px_e;
                        int ch = ntc * 16 + n;
                        hbcf[(size_t)site * 32 + ch] = f2bf(hn[r]);
                        __builtin_nontemporal_store(hn[r],
                            &out[((size_t)((b * Tn + t) * SITES) + site) * 64 + dir * 32 + ch]);
                    }
                }
            }
        }
    }
}

extern "C" void kernel_launch(void* const* d_in, const int* in_sizes, int n_in,
                              void* d_out, int out_size, void* d_ws, size_t ws_size,
                              hipStream_t stream)
{
    const float* x     = (const float*)d_in[0];
    const float* Wx_f  = (const float*)d_in[1];
    const float* b_f   = (const float*)d_in[2];
    const float* Wzr_f = (const float*)d_in[3];
    const float* Wh_f  = (const float*)d_in[4];
    const float* Wx_b  = (const float*)d_in[5];
    const float* b_b   = (const float*)d_in[6];
    const float* Wzr_b = (const float*)d_in[7];
    const float* Wh_b  = (const float*)d_in[8];
    float* out = (float*)d_out;

    char* w = (char*)d_ws;
    short* hb0  = (short*)w;  w += (size_t)HSZ * 2;
    short* hb1  = (short*)w;  w += (size_t)HSZ * 2;
    float* hfC0 = (float*)w;  w += (size_t)CTILE * 4;
    float* hfC1 = (float*)w;  w += (size_t)CTILE * 4;
    short* xb8  = (short*)w;  w += (size_t)NPX * 8 * 2;
    short* bopA = (short*)w;  w += (size_t)NA * 2;
    short* bopB = (short*)w;  w += (size_t)NB * 2;
    // total ~19.8 MB

    prep_kernel<<<(PREP_TOT + BLK - 1) / BLK, BLK, 0, stream>>>(
        Wzr_f, Wzr_b, Wh_f, Wh_b, Wx_f, Wx_b, x, bopA, bopB, xb8);

    for (int s = 0; s < Tn; s++) {
        const short* hbp = (s & 1) ? hb0 : hb1;
        short*       hbc = (s & 1) ? hb1 : hb0;
        const float* hfp = (s & 1) ? hfC0 : hfC1;
        float*       hfc = (s & 1) ? hfC1 : hfC0;
        step_kernel<<<GRID, BLK, 0, stream>>>(xb8, bopA, bopB, b_f, b_b,
                                              hbp, hbc, hfp, hfc, out, s);
    }
}